// Round 8
// baseline (644.685 us; speedup 1.0000x reference)
//
#include <hip/hip_runtime.h>
#include <hip/hip_bf16.h>
#include <hip/hip_fp16.h>

constexpr int INC  = 32;
constexpr int OUTC = 32;
constexpr int CHROWS = 256;   // rows per output chunk
constexpr int NPART  = 8;     // i-range parts per k (fill blocks per k)
constexpr int CAPP   = 80;    // records per (k,chunk,part): mean 32 + 8.5 sigma
constexpr int NCHMAX = 2048;  // max chunks (LDS cursor array)
constexpr int ACCW   = 17;    // u64 words per acc row (16 ch-pairs + 1 pad)

typedef __bf16 bf16x8 __attribute__((ext_vector_type(8)));
typedef float  f32x4  __attribute__((ext_vector_type(4)));
typedef __attribute__((address_space(3))) unsigned long long lds_u64;
typedef __attribute__((address_space(3))) unsigned           lds_u32;

// ---------------------------------------------------------------------------
// R12: R10 proved the DS-pipe fix (conv 2057->223us; AS3 atomics are REQUIRED
// on gfx950 — generic-pointer atomicAdd on __shared__ lowers to LDS-aperture
// FLAT atomics at the ~168 G op/s global wall). Remaining: fill's 8x index
// read amplification (691 MB for 86.4 MB of data). Fix: partition fill by
// (k, i-range part) — each index read ONCE device-wide; records binned into
// per-(k,chunk,part) sub-segments (cap 80, single-writer, AS3 LDS cursors).
// Conv iterates the 8 sub-segments per bucket (B-frags hoisted per k).
// enc2 clamps dropped (|contrib| <= ~1.6 << i32 overflow bound).
// ---------------------------------------------------------------------------

__device__ __forceinline__ void lds_add_u64(unsigned long long* p,
                                            unsigned long long v) {
    __hip_atomic_fetch_add((lds_u64*)p, v,
                           __ATOMIC_RELAXED, __HIP_MEMORY_SCOPE_WORKGROUP);
}
__device__ __forceinline__ unsigned lds_add_u32(unsigned* p, unsigned v) {
    return __hip_atomic_fetch_add((lds_u32*)p, v,
                                  __ATOMIC_RELAXED, __HIP_MEMORY_SCOPE_WORKGROUP);
}

__device__ __forceinline__ unsigned long long enc2(float a, float b) {
    const int q0 = __float2int_rn(a * 65536.0f);
    const int q1 = __float2int_rn(b * 65536.0f);
    return (unsigned long long)((long long)q0 + ((long long)q1 << 32));
}

__global__ __launch_bounds__(256) void prep_feats(
    const float* __restrict__ f, __bf16* __restrict__ fb, int total8)
{
    int i = blockIdx.x * 256 + threadIdx.x;
    const int stride = gridDim.x * 256;
    for (; i < total8; i += stride) {
        const float4* p = (const float4*)(f + (size_t)i * 8);
        const float4 a = p[0], b = p[1];
        bf16x8 v;
        v[0] = (__bf16)a.x; v[1] = (__bf16)a.y; v[2] = (__bf16)a.z; v[3] = (__bf16)a.w;
        v[4] = (__bf16)b.x; v[5] = (__bf16)b.y; v[6] = (__bf16)b.z; v[7] = (__bf16)b.w;
        *(bf16x8*)(fb + (size_t)i * 8) = v;
    }
}

// One block per (k, part): scans i in [p*N/8,(p+1)*N/8), single-writer into
// per-(k,chunk,part) sub-segments. Each index element read ONCE device-wide.
__global__ __launch_bounds__(1024) void fill_parts(
    const int* __restrict__ in_idx,   // [K][N]
    const int* __restrict__ out_idx,  // [K][N]
    unsigned* __restrict__ recsB,     // [K*nchunkpad*8][CAPP]; rec=iin|lrow<<19
    unsigned* __restrict__ cntB,      // [K*nchunkpad*8]
    int N, int nchunk, int nchunkpad)
{
    __shared__ unsigned cur[NCHMAX];
    const int p = blockIdx.x, k = blockIdx.y;
    const int tid = threadIdx.x;
    for (int c = tid; c < nchunk; c += 1024) cur[c] = 0u;
    __syncthreads();

    const int part_n  = N / NPART;
    const int ibeg    = p * part_n;
    const int iend    = ibeg + part_n;
    const int* iin_p  = in_idx  + (size_t)k * N;
    const int* iout_p = out_idx + (size_t)k * N;
    const size_t kbase8 = (size_t)k * nchunkpad * NPART;

    for (int i0 = ibeg + tid * 4; i0 < iend; i0 += 4096) {
        const int4 ov = *(const int4*)(iout_p + i0);
        const int4 iv = *(const int4*)(iin_p + i0);
        const unsigned o[4]  = {(unsigned)ov.x, (unsigned)ov.y,
                                (unsigned)ov.z, (unsigned)ov.w};
        const unsigned ii[4] = {(unsigned)iv.x, (unsigned)iv.y,
                                (unsigned)iv.z, (unsigned)iv.w};
#pragma unroll
        for (int j = 0; j < 4; ++j) {
            const unsigned c    = o[j] >> 8;
            const unsigned lrow = o[j] & 255u;
            const unsigned pos  = lds_add_u32(&cur[c], 1u);
            if (pos < (unsigned)CAPP)
                recsB[(kbase8 + (size_t)c * NPART + p) * CAPP + pos]
                    = ii[j] | (lrow << 19);
        }
    }
    __syncthreads();
    for (int c = tid; c < nchunk; c += 1024)
        cntB[kbase8 + (size_t)c * NPART + p] = min(cur[c], (unsigned)CAPP);
}

// Block per 256-row chunk: 9 waves x 3 k's, u64 fixed-point LDS acc via
// ds_add_u64 (AS3), 8 sub-segments per (k,chunk), fused BN+ReLU.
template<bool BF16F>
__global__ __launch_bounds__(576) void conv_chunk(
    const float*  __restrict__ feats,
    const __bf16* __restrict__ fbf,
    const float*  __restrict__ wkern,
    const unsigned* __restrict__ recsB,
    const unsigned* __restrict__ cntB,
    const float* __restrict__ gamma, const float* __restrict__ beta,
    const float* __restrict__ mean,  const float* __restrict__ var,
    float* __restrict__ out, int N, int nchunkpad)
{
    __shared__ unsigned long long accw[(CHROWS + 1) * ACCW]; // +1 dump row
    const int tid = threadIdx.x;
    for (int i = tid; i < (CHROWS + 1) * ACCW; i += 576) accw[i] = 0ull;
    __syncthreads();

    const int c    = blockIdx.x;
    const int wid  = tid >> 6;          // 0..8
    const int lane = tid & 63;
    const int col  = lane & 15;
    const int quad = lane >> 4;

#pragma unroll 1
    for (int kk = 0; kk < 3; ++kk) {
        const int k = wid + kk * 9;     // 9 waves x 3 = 27
        const size_t bidx8 = ((size_t)k * nchunkpad + c) * NPART;

        const float* wk = wkern + (size_t)k * (INC * OUTC);
        bf16x8 b0, b1;   // column-permuted: acc0 -> ch 2*col, acc1 -> 2*col+1
#pragma unroll
        for (int j = 0; j < 8; ++j) {
            const float2 w2 = *(const float2*)(wk + (quad * 8 + j) * OUTC + 2 * col);
            b0[j] = (__bf16)w2.x;
            b1[j] = (__bf16)w2.y;
        }

#pragma unroll 1
        for (int p = 0; p < NPART; ++p) {
            const int cnt = (int)cntB[bidx8 + p];
            if (cnt == 0) continue;
            const unsigned* seg = recsB + (bidx8 + p) * CAPP;
            const int ntile = (cnt + 15) >> 4;

            auto do_tile = [&](int t) {
                const int sbase = t << 4;
                const unsigned ra = seg[sbase + col];
                const unsigned iidx = (sbase + col < cnt) ? (ra & 0x7FFFFu) : 0u;
                bf16x8 a;
                if constexpr (BF16F) {
                    a = *(const bf16x8*)(fbf + (size_t)iidx * INC + quad * 8);
                } else {
                    const float4* ap = (const float4*)(feats + (size_t)iidx * INC + quad * 8);
                    const float4 alo = ap[0], ahi = ap[1];
                    a[0] = (__bf16)alo.x; a[1] = (__bf16)alo.y;
                    a[2] = (__bf16)alo.z; a[3] = (__bf16)alo.w;
                    a[4] = (__bf16)ahi.x; a[5] = (__bf16)ahi.y;
                    a[6] = (__bf16)ahi.z; a[7] = (__bf16)ahi.w;
                }
                const uint4 rv = *(const uint4*)(seg + sbase + quad * 4);
                f32x4 acc0 = {0.f, 0.f, 0.f, 0.f};
                f32x4 acc1 = {0.f, 0.f, 0.f, 0.f};
                acc0 = __builtin_amdgcn_mfma_f32_16x16x32_bf16(a, b0, acc0, 0, 0, 0);
                acc1 = __builtin_amdgcn_mfma_f32_16x16x32_bf16(a, b1, acc1, 0, 0, 0);
                const unsigned rr[4] = { rv.x, rv.y, rv.z, rv.w };
#pragma unroll
                for (int r = 0; r < 4; ++r) {
                    const int idx  = sbase + quad * 4 + r;
                    const int lrow = (idx < cnt) ? (int)((rr[r] >> 19) & 255u) : CHROWS;
                    lds_add_u64(&accw[lrow * ACCW + col], enc2(acc0[r], acc1[r]));
                }
            };

            int t = 0;
            for (; t + 2 <= ntile; t += 2) {
                const int s0 = (t << 4), s1 = s0 + 16;
                const unsigned ra0 = seg[s0 + col];
                const unsigned ra1 = seg[s1 + col];
                const uint4 rv0 = *(const uint4*)(seg + s0 + quad * 4);
                const uint4 rv1 = *(const uint4*)(seg + s1 + quad * 4);
                const unsigned i0 = (s0 + col < cnt) ? (ra0 & 0x7FFFFu) : 0u;
                const unsigned i1 = (s1 + col < cnt) ? (ra1 & 0x7FFFFu) : 0u;

                bf16x8 a0, a1;
                if constexpr (BF16F) {
                    a0 = *(const bf16x8*)(fbf + (size_t)i0 * INC + quad * 8);
                    a1 = *(const bf16x8*)(fbf + (size_t)i1 * INC + quad * 8);
                } else {
                    const float4* p0 = (const float4*)(feats + (size_t)i0 * INC + quad * 8);
                    const float4* p1 = (const float4*)(feats + (size_t)i1 * INC + quad * 8);
                    const float4 a0lo = p0[0], a0hi = p0[1];
                    const float4 a1lo = p1[0], a1hi = p1[1];
                    a0[0] = (__bf16)a0lo.x; a0[1] = (__bf16)a0lo.y;
                    a0[2] = (__bf16)a0lo.z; a0[3] = (__bf16)a0lo.w;
                    a0[4] = (__bf16)a0hi.x; a0[5] = (__bf16)a0hi.y;
                    a0[6] = (__bf16)a0hi.z; a0[7] = (__bf16)a0hi.w;
                    a1[0] = (__bf16)a1lo.x; a1[1] = (__bf16)a1lo.y;
                    a1[2] = (__bf16)a1lo.z; a1[3] = (__bf16)a1lo.w;
                    a1[4] = (__bf16)a1hi.x; a1[5] = (__bf16)a1hi.y;
                    a1[6] = (__bf16)a1hi.z; a1[7] = (__bf16)a1hi.w;
                }

                f32x4 c00 = {0.f, 0.f, 0.f, 0.f};
                f32x4 c01 = {0.f, 0.f, 0.f, 0.f};
                f32x4 c10 = {0.f, 0.f, 0.f, 0.f};
                f32x4 c11 = {0.f, 0.f, 0.f, 0.f};
                c00 = __builtin_amdgcn_mfma_f32_16x16x32_bf16(a0, b0, c00, 0, 0, 0);
                c01 = __builtin_amdgcn_mfma_f32_16x16x32_bf16(a0, b1, c01, 0, 0, 0);
                c10 = __builtin_amdgcn_mfma_f32_16x16x32_bf16(a1, b0, c10, 0, 0, 0);
                c11 = __builtin_amdgcn_mfma_f32_16x16x32_bf16(a1, b1, c11, 0, 0, 0);

                const unsigned rr0[4] = { rv0.x, rv0.y, rv0.z, rv0.w };
                const unsigned rr1[4] = { rv1.x, rv1.y, rv1.z, rv1.w };
#pragma unroll
                for (int r = 0; r < 4; ++r) {
                    const int idx0  = s0 + quad * 4 + r;
                    const int lrow0 = (idx0 < cnt) ? (int)((rr0[r] >> 19) & 255u) : CHROWS;
                    lds_add_u64(&accw[lrow0 * ACCW + col], enc2(c00[r], c01[r]));
                }
#pragma unroll
                for (int r = 0; r < 4; ++r) {
                    const int idx1  = s1 + quad * 4 + r;
                    const int lrow1 = (idx1 < cnt) ? (int)((rr1[r] >> 19) & 255u) : CHROWS;
                    lds_add_u64(&accw[lrow1 * ACCW + col], enc2(c10[r], c11[r]));
                }
            }
            for (; t < ntile; ++t) do_tile(t);
        }
    }
    __syncthreads();

    // Decode + fused BN + ReLU: one u64 word (2 channels) per thread.
    if (tid < 512) {
        const int p  = tid & 15;            // ch-pair index
        const int c0 = 2 * p;
        const int r0 = tid >> 4;            // 0..31
        const float s0 = gamma[c0]     * rsqrtf(var[c0]     + 1e-5f);
        const float s1 = gamma[c0 + 1] * rsqrtf(var[c0 + 1] + 1e-5f);
        const float q0 = beta[c0]     - mean[c0]     * s0;
        const float q1 = beta[c0 + 1] - mean[c0 + 1] * s1;
#pragma unroll
        for (int it = 0; it < CHROWS / 32; ++it) {
            const int row  = it * 32 + r0;
            const int grow = c * CHROWS + row;
            if (grow < N) {
                long long t = (long long)accw[row * ACCW + p];
                const int d0 = (int)(unsigned)(t & 0xFFFFFFFFll);
                const int d1 = (int)((t - (long long)d0) >> 32);
                float2 o;
                o.x = fmaxf(fmaf((float)d0 * (1.f / 65536.f), s0, q0), 0.f);
                o.y = fmaxf(fmaf((float)d1 * (1.f / 65536.f), s1, q1), 0.f);
                *(float2*)(out + (size_t)grow * OUTC + c0) = o;
            }
        }
    }
}

// ------------------- pk-f16 atomic path (R3, 693us, fallback) ---------------
__global__ __launch_bounds__(256) void scatter_conv_mfma_pk(
    const float* __restrict__ feats,
    const float* __restrict__ wkern,
    const int*   __restrict__ in_idx,
    const int*   __restrict__ out_idx,
    __half2*     __restrict__ ws,
    int N)
{
    const int k    = blockIdx.y;
    const int lane = threadIdx.x & 63;
    const int col  = lane & 15;
    const int quad = lane >> 4;

    const int wave   = blockIdx.x * 4 + (threadIdx.x >> 6);
    const int nwaves = gridDim.x * 4;

    const float* wk = wkern + (size_t)k * (INC * OUTC);
    bf16x8 b0, b1;
#pragma unroll
    for (int j = 0; j < 8; ++j) {
        const int kk = quad * 8 + j;
        b0[j] = (__bf16)wk[kk * OUTC + 2 * col];
        b1[j] = (__bf16)wk[kk * OUTC + 2 * col + 1];
    }

    const int* iin_p  = in_idx  + (size_t)k * N;
    const int* iout_p = out_idx + (size_t)k * N;
    const int  ntiles = N >> 4;

    for (int t = wave; t < ntiles; t += nwaves) {
        const int base = t << 4;
        const int iin = iin_p[base + col];
        int orow[4];
#pragma unroll
        for (int r = 0; r < 4; ++r) orow[r] = iout_p[base + quad * 4 + r];

        const float4* ap = (const float4*)(feats + (size_t)iin * INC + quad * 8);
        const float4 a_lo = ap[0];
        const float4 a_hi = ap[1];
        bf16x8 a;
        a[0] = (__bf16)a_lo.x; a[1] = (__bf16)a_lo.y;
        a[2] = (__bf16)a_lo.z; a[3] = (__bf16)a_lo.w;
        a[4] = (__bf16)a_hi.x; a[5] = (__bf16)a_hi.y;
        a[6] = (__bf16)a_hi.z; a[7] = (__bf16)a_hi.w;

        f32x4 acc0 = {0.f, 0.f, 0.f, 0.f};
        f32x4 acc1 = {0.f, 0.f, 0.f, 0.f};
        acc0 = __builtin_amdgcn_mfma_f32_16x16x32_bf16(a, b0, acc0, 0, 0, 0);
        acc1 = __builtin_amdgcn_mfma_f32_16x16x32_bf16(a, b1, acc1, 0, 0, 0);

#pragma unroll
        for (int r = 0; r < 4; ++r) {
            __half2 v = __halves2half2(__float2half(acc0[r]), __float2half(acc1[r]));
            unsafeAtomicAdd(ws + (size_t)orow[r] * 16 + col, v);
        }
    }
}

__global__ __launch_bounds__(256) void bn_relu_f16(
    const __half2* __restrict__ ws,
    float* __restrict__ out,
    const float* __restrict__ gamma,
    const float* __restrict__ beta,
    const float* __restrict__ mean,
    const float* __restrict__ var,
    int total2)
{
    const int tid    = blockIdx.x * blockDim.x + threadIdx.x;
    const int stride = gridDim.x * blockDim.x;
    const int p      = tid & 15;
    const int c0     = 2 * p;

    float s0 = gamma[c0]     * rsqrtf(var[c0]     + 1e-5f);
    float s1 = gamma[c0 + 1] * rsqrtf(var[c0 + 1] + 1e-5f);
    float q0 = beta[c0]     - mean[c0]     * s0;
    float q1 = beta[c0 + 1] - mean[c0 + 1] * s1;

    float2* po = (float2*)out;
    for (int i = tid; i < total2; i += stride) {
        const __half2 h = ws[i];
        float2 v;
        v.x = fmaxf(fmaf(__low2float(h),  s0, q0), 0.0f);
        v.y = fmaxf(fmaf(__high2float(h), s1, q1), 0.0f);
        po[i] = v;
    }
}

// ------------------------- fp32 fallback (R2 path) -------------------------
__global__ __launch_bounds__(256) void scatter_conv_mfma_f32(
    const float* __restrict__ feats,
    const float* __restrict__ wkern,
    const int*   __restrict__ in_idx,
    const int*   __restrict__ out_idx,
    float*       __restrict__ out,
    int N)
{
    const int k    = blockIdx.y;
    const int lane = threadIdx.x & 63;
    const int col  = lane & 15;
    const int quad = lane >> 4;
    const int wave   = blockIdx.x * 4 + (threadIdx.x >> 6);
    const int nwaves = gridDim.x * 4;

    const float* wk = wkern + (size_t)k * (INC * OUTC);
    bf16x8 b0, b1;
#pragma unroll
    for (int j = 0; j < 8; ++j) {
        const int kk = quad * 8 + j;
        b0[j] = (__bf16)wk[kk * OUTC + col];
        b1[j] = (__bf16)wk[kk * OUTC + 16 + col];
    }

    const int* iin_p  = in_idx  + (size_t)k * N;
    const int* iout_p = out_idx + (size_t)k * N;
    const int  ntiles = N >> 4;

    for (int t = wave; t < ntiles; t += nwaves) {
        const int base = t << 4;
        const int iin = iin_p[base + col];
        int orow[4];
#pragma unroll
        for (int r = 0; r < 4; ++r) orow[r] = iout_p[base + quad * 4 + r];

        const float4* ap = (const float4*)(feats + (size_t)iin * INC + quad * 8);
        const float4 a_lo = ap[0];
        const float4 a_hi = ap[1];
        bf16x8 a;
        a[0] = (__bf16)a_lo.x; a[1] = (__bf16)a_lo.y;
        a[2] = (__bf16)a_lo.z; a[3] = (__bf16)a_lo.w;
        a[4] = (__bf16)a_hi.x; a[5] = (__bf16)a_hi.y;
        a[6] = (__bf16)a_hi.z; a[7] = (__bf16)a_hi.w;

        f32x4 acc0 = {0.f, 0.f, 0.f, 0.f};
        f32x4 acc1 = {0.f, 0.f, 0.f, 0.f};
        acc0 = __builtin_amdgcn_mfma_f32_16x16x32_bf16(a, b0, acc0, 0, 0, 0);
        acc1 = __builtin_amdgcn_mfma_f32_16x16x32_bf16(a, b1, acc1, 0, 0, 0);

#pragma unroll
        for (int r = 0; r < 4; ++r) {
            float* dst = out + (size_t)orow[r] * OUTC + col;
            unsafeAtomicAdd(dst,      acc0[r]);
            unsafeAtomicAdd(dst + 16, acc1[r]);
        }
    }
}

__global__ __launch_bounds__(256) void bn_relu_f32_inplace(
    float* __restrict__ out,
    const float* __restrict__ gamma,
    const float* __restrict__ beta,
    const float* __restrict__ mean,
    const float* __restrict__ var,
    int total4)
{
    const int tid    = blockIdx.x * blockDim.x + threadIdx.x;
    const int stride = gridDim.x * blockDim.x;
    const int c0     = (tid & 7) << 2;

    float s[4], b[4];
#pragma unroll
    for (int j = 0; j < 4; ++j) {
        const int c = c0 + j;
        s[j] = gamma[c] * rsqrtf(var[c] + 1e-5f);
        b[j] = beta[c] - mean[c] * s[j];
    }

    float4* p = (float4*)out;
    for (int i = tid; i < total4; i += stride) {
        float4 v = p[i];
        v.x = fmaxf(fmaf(v.x, s[0], b[0]), 0.0f);
        v.y = fmaxf(fmaf(v.y, s[1], b[1]), 0.0f);
        v.z = fmaxf(fmaf(v.z, s[2], b[2]), 0.0f);
        v.w = fmaxf(fmaf(v.w, s[3], b[3]), 0.0f);
        p[i] = v;
    }
}

extern "C" void kernel_launch(void* const* d_in, const int* in_sizes, int n_in,
                              void* d_out, int out_size, void* d_ws, size_t ws_size,
                              hipStream_t stream) {
    const float* feats   = (const float*)d_in[0];
    const float* wkern   = (const float*)d_in[1];
    const float* gamma   = (const float*)d_in[2];
    const float* beta    = (const float*)d_in[3];
    const float* mean    = (const float*)d_in[4];
    const float* var     = (const float*)d_in[5];
    const int*   in_idx  = (const int*)d_in[6];
    const int*   out_idx = (const int*)d_in[7];
    float*       out     = (float*)d_out;

    const int N = in_sizes[0] / INC;                  // 400000
    const int K = in_sizes[1] / (INC * OUTC);         // 27

    const int nchunk    = (N + CHROWS - 1) / CHROWS;  // 1563
    const int nchunkpad = (nchunk + 31) & ~31;        // 1568

    auto al = [](size_t x) { return (x + 255) & ~(size_t)255; };
    size_t off = 0;
    const size_t cntB_off  = off;
    off = al(off + (size_t)K * nchunkpad * NPART * 4);           // 1.35 MB
    const size_t recsB_off = off;
    off = al(off + (size_t)K * nchunkpad * NPART * CAPP * 4);    // 108.4 MB
    const size_t need_core = off;
    const size_t fbf_off   = off;
    const size_t need_full = off + al((size_t)N * INC * 2);      // ~135.4 MB
    const size_t need_pk   = (size_t)N * OUTC * sizeof(__half);

    const bool chunk_ok = (N <= (1 << 19)) && (N % (NPART * 4) == 0) &&
                          (nchunk <= NCHMAX) && (K == 27);

    if (chunk_ok && ws_size >= need_core) {
        char* base = (char*)d_ws;
        unsigned* cntB  = (unsigned*)(base + cntB_off);
        unsigned* recsB = (unsigned*)(base + recsB_off);

        const bool use_bf16 = ws_size >= need_full;
        if (use_bf16) {
            __bf16* fbf = (__bf16*)(base + fbf_off);
            prep_feats<<<768, 256, 0, stream>>>(feats, fbf, N * 4);
            fill_parts<<<dim3(NPART, K), 1024, 0, stream>>>(
                in_idx, out_idx, recsB, cntB, N, nchunk, nchunkpad);
            conv_chunk<true><<<nchunk, 576, 0, stream>>>(
                feats, fbf, wkern, recsB, cntB, gamma, beta, mean, var,
                out, N, nchunkpad);
        } else {
            fill_parts<<<dim3(NPART, K), 1024, 0, stream>>>(
                in_idx, out_idx, recsB, cntB, N, nchunk, nchunkpad);
            conv_chunk<false><<<nchunk, 576, 0, stream>>>(
                feats, nullptr, wkern, recsB, cntB, gamma, beta, mean, var,
                out, N, nchunkpad);
        }
    } else if (ws_size >= need_pk) {
        __half2* acc = (__half2*)d_ws;
        hipMemsetAsync(acc, 0, need_pk, stream);
        dim3 grid(80, K);
        scatter_conv_mfma_pk<<<grid, 256, 0, stream>>>(
            feats, wkern, in_idx, out_idx, acc, N);
        bn_relu_f16<<<1024, 256, 0, stream>>>(acc, out, gamma, beta, mean, var, N * 16);
    } else {
        hipMemsetAsync(out, 0, (size_t)out_size * sizeof(float), stream);
        dim3 grid(80, K);
        scatter_conv_mfma_f32<<<grid, 256, 0, stream>>>(
            feats, wkern, in_idx, out_idx, out, N);
        bn_relu_f32_inplace<<<1024, 256, 0, stream>>>(
            out, gamma, beta, mean, var, out_size / 4);
    }
}

// Round 9
// 551.812 us; speedup vs baseline: 1.1683x; 1.1683x over previous
//
#include <hip/hip_runtime.h>
#include <hip/hip_bf16.h>
#include <hip/hip_fp16.h>

constexpr int INC  = 32;
constexpr int OUTC = 32;
constexpr int CHROWS  = 256;   // rows per output chunk
constexpr int NSLICE  = 8;     // one fill block per (k, slice)
constexpr int CAPB    = 384;   // per-(k,chunk) records: mean 256 + 8 sigma
constexpr int CPS_MAX = 208;   // max chunks per slice (LDS cursor array)
constexpr int ACCW    = 17;    // u64 words per acc row (16 ch-pairs + 1 pad)

typedef __bf16 bf16x8 __attribute__((ext_vector_type(8)));
typedef float  f32x4  __attribute__((ext_vector_type(4)));
typedef __attribute__((address_space(3))) unsigned long long lds_u64;
typedef __attribute__((address_space(3))) unsigned           lds_u32;

// ---------------------------------------------------------------------------
// R13: R12 showed (a) fill's read amplification is irrelevant (8x fewer reads,
// same wall time) and (b) conv fragmentation cost +80us (8 sub-segments =>
// ~25% tile padding). Non-conv time is FIXED ~330us across all fill designs
// vs ~110us for the 3-dispatch pk path => suspect dispatch/graph overhead.
// This round: (1) revert conv to the unfragmented R10 form (proven 223us),
// (2) fuse prep_feats INTO fill (each fill block converts its 1/216 share of
// feats before binning; conv starts only after the kernel completes, so no
// sync needed) => 2 dispatches instead of 3. AS3 DS atomics everywhere
// (gfx950 lesson: generic-pointer atomics on __shared__ take the flat path
// at the ~168 G op/s global wall; explicit address_space(3) is REQUIRED).
// ---------------------------------------------------------------------------

__device__ __forceinline__ void lds_add_u64(unsigned long long* p,
                                            unsigned long long v) {
    __hip_atomic_fetch_add((lds_u64*)p, v,
                           __ATOMIC_RELAXED, __HIP_MEMORY_SCOPE_WORKGROUP);
}
__device__ __forceinline__ unsigned lds_add_u32(unsigned* p, unsigned v) {
    return __hip_atomic_fetch_add((lds_u32*)p, v,
                                  __ATOMIC_RELAXED, __HIP_MEMORY_SCOPE_WORKGROUP);
}

__device__ __forceinline__ unsigned long long enc2(float a, float b) {
    const int q0 = __float2int_rn(a * 65536.0f);
    const int q1 = __float2int_rn(b * 65536.0f);
    return (unsigned long long)((long long)q0 + ((long long)q1 << 32));
}

// One block per (k, slice): converts its share of feats to bf16 (fused prep),
// then single-writer binning into its exclusive recsB segment.
template<bool DO_PREP>
__global__ __launch_bounds__(1024) void fill_fused(
    const float* __restrict__ feats,  // [N][32]
    __bf16*      __restrict__ fbf,    // [N][32] bf16 (written iff DO_PREP)
    const int*   __restrict__ in_idx, // [K][N]
    const int*   __restrict__ out_idx,// [K][N]
    unsigned* __restrict__ recsB,     // [K*nchunkpad][CAPB]; rec = iin|lrow<<19
    unsigned* __restrict__ cntB,      // [K*nchunkpad]
    int N, int cps, int slice_rows, int total8)
{
    __shared__ unsigned cur[CPS_MAX];
    const int s = blockIdx.x, k = blockIdx.y;
    const int tid = threadIdx.x;
    for (int c = tid; c < cps; c += 1024) cur[c] = 0u;

    if constexpr (DO_PREP) {
        // convert this block's 1/216 share of feats (8 floats per item)
        const int nb    = gridDim.x * gridDim.y;       // 216
        const int b     = k * gridDim.x + s;
        const int share = (total8 + nb - 1) / nb;
        const int beg   = b * share;
        const int end   = min(total8, beg + share);
        for (int i = beg + tid; i < end; i += 1024) {
            const float4* p = (const float4*)(feats + (size_t)i * 8);
            const float4 a = p[0], bb = p[1];
            bf16x8 v;
            v[0] = (__bf16)a.x;  v[1] = (__bf16)a.y;
            v[2] = (__bf16)a.z;  v[3] = (__bf16)a.w;
            v[4] = (__bf16)bb.x; v[5] = (__bf16)bb.y;
            v[6] = (__bf16)bb.z; v[7] = (__bf16)bb.w;
            *(bf16x8*)(fbf + (size_t)i * 8) = v;
        }
    }
    __syncthreads();

    const int* iin_p  = in_idx  + (size_t)k * N;
    const int* iout_p = out_idx + (size_t)k * N;
    const int nchunkpad = NSLICE * cps;
    const unsigned lo = (unsigned)(s * slice_rows);
    const unsigned hi = lo + (unsigned)slice_rows;
    const size_t segbase = ((size_t)k * nchunkpad + (size_t)s * cps) * CAPB;

    for (int i0 = tid * 4; i0 < N; i0 += 4096) {
        const int4 ov = *(const int4*)(iout_p + i0);
        const int4 iv = *(const int4*)(iin_p + i0);
        const unsigned o[4]  = {(unsigned)ov.x, (unsigned)ov.y,
                                (unsigned)ov.z, (unsigned)ov.w};
        const unsigned ii[4] = {(unsigned)iv.x, (unsigned)iv.y,
                                (unsigned)iv.z, (unsigned)iv.w};
#pragma unroll
        for (int j = 0; j < 4; ++j) {
            if (o[j] >= lo && o[j] < hi) {
                const unsigned olo  = o[j] - lo;
                const unsigned c    = olo >> 8;     // local chunk
                const unsigned lrow = olo & 255u;
                const unsigned pos  = lds_add_u32(&cur[c], 1u);
                if (pos < (unsigned)CAPB)
                    recsB[segbase + (size_t)c * CAPB + pos] = ii[j] | (lrow << 19);
            }
        }
    }
    __syncthreads();
    for (int c = tid; c < cps; c += 1024)
        cntB[(size_t)k * nchunkpad + (size_t)s * cps + c] =
            min(cur[c], (unsigned)CAPB);
}

// Block per 256-row chunk: 9 waves x 3 k's, u64 fixed-point LDS acc via
// ds_add_u64 (AS3), 2-deep pipelined gathers, fused BN+ReLU. (R10-proven.)
template<bool BF16F>
__global__ __launch_bounds__(576) void conv_chunk(
    const float*  __restrict__ feats,
    const __bf16* __restrict__ fbf,
    const float*  __restrict__ wkern,
    const unsigned* __restrict__ recsB,
    const unsigned* __restrict__ cntB,
    const float* __restrict__ gamma, const float* __restrict__ beta,
    const float* __restrict__ mean,  const float* __restrict__ var,
    float* __restrict__ out, int N, int nchunkpad)
{
    __shared__ unsigned long long accw[(CHROWS + 1) * ACCW]; // +1 dump row
    const int tid = threadIdx.x;
    for (int i = tid; i < (CHROWS + 1) * ACCW; i += 576) accw[i] = 0ull;
    __syncthreads();

    const int c    = blockIdx.x;
    const int wid  = tid >> 6;          // 0..8
    const int lane = tid & 63;
    const int col  = lane & 15;
    const int quad = lane >> 4;

#pragma unroll
    for (int kk = 0; kk < 3; ++kk) {
        const int k = wid + kk * 9;     // 9 waves x 3 = 27
        const int bidx = k * nchunkpad + c;
        const int cnt = (int)cntB[bidx];
        if (cnt == 0) continue;
        const unsigned* seg = recsB + (size_t)bidx * CAPB;

        const float* wk = wkern + (size_t)k * (INC * OUTC);
        bf16x8 b0, b1;   // column-permuted: acc0 -> ch 2*col, acc1 -> 2*col+1
#pragma unroll
        for (int j = 0; j < 8; ++j) {
            const float2 w2 = *(const float2*)(wk + (quad * 8 + j) * OUTC + 2 * col);
            b0[j] = (__bf16)w2.x;
            b1[j] = (__bf16)w2.y;
        }

        const int ntile = (cnt + 15) >> 4;

        auto do_tile = [&](int t) {
            const int sbase = t << 4;
            const unsigned ra = seg[sbase + col];
            const unsigned iidx = (sbase + col < cnt) ? (ra & 0x7FFFFu) : 0u;
            bf16x8 a;
            if constexpr (BF16F) {
                a = *(const bf16x8*)(fbf + (size_t)iidx * INC + quad * 8);
            } else {
                const float4* ap = (const float4*)(feats + (size_t)iidx * INC + quad * 8);
                const float4 alo = ap[0], ahi = ap[1];
                a[0] = (__bf16)alo.x; a[1] = (__bf16)alo.y;
                a[2] = (__bf16)alo.z; a[3] = (__bf16)alo.w;
                a[4] = (__bf16)ahi.x; a[5] = (__bf16)ahi.y;
                a[6] = (__bf16)ahi.z; a[7] = (__bf16)ahi.w;
            }
            const uint4 rv = *(const uint4*)(seg + sbase + quad * 4);
            f32x4 acc0 = {0.f, 0.f, 0.f, 0.f};
            f32x4 acc1 = {0.f, 0.f, 0.f, 0.f};
            acc0 = __builtin_amdgcn_mfma_f32_16x16x32_bf16(a, b0, acc0, 0, 0, 0);
            acc1 = __builtin_amdgcn_mfma_f32_16x16x32_bf16(a, b1, acc1, 0, 0, 0);
            const unsigned rr[4] = { rv.x, rv.y, rv.z, rv.w };
#pragma unroll
            for (int r = 0; r < 4; ++r) {
                const int idx  = sbase + quad * 4 + r;
                const int lrow = (idx < cnt) ? (int)((rr[r] >> 19) & 255u) : CHROWS;
                lds_add_u64(&accw[lrow * ACCW + col], enc2(acc0[r], acc1[r]));
            }
        };

        int t = 0;
        for (; t + 2 <= ntile; t += 2) {
            const int s0 = t << 4, s1 = s0 + 16;
            const unsigned ra0 = seg[s0 + col];
            const unsigned ra1 = seg[s1 + col];
            const uint4 rv0 = *(const uint4*)(seg + s0 + quad * 4);
            const uint4 rv1 = *(const uint4*)(seg + s1 + quad * 4);
            const unsigned i0 = (s0 + col < cnt) ? (ra0 & 0x7FFFFu) : 0u;
            const unsigned i1 = (s1 + col < cnt) ? (ra1 & 0x7FFFFu) : 0u;

            bf16x8 a0, a1;
            if constexpr (BF16F) {
                a0 = *(const bf16x8*)(fbf + (size_t)i0 * INC + quad * 8);
                a1 = *(const bf16x8*)(fbf + (size_t)i1 * INC + quad * 8);
            } else {
                const float4* p0 = (const float4*)(feats + (size_t)i0 * INC + quad * 8);
                const float4* p1 = (const float4*)(feats + (size_t)i1 * INC + quad * 8);
                const float4 a0lo = p0[0], a0hi = p0[1];
                const float4 a1lo = p1[0], a1hi = p1[1];
                a0[0] = (__bf16)a0lo.x; a0[1] = (__bf16)a0lo.y;
                a0[2] = (__bf16)a0lo.z; a0[3] = (__bf16)a0lo.w;
                a0[4] = (__bf16)a0hi.x; a0[5] = (__bf16)a0hi.y;
                a0[6] = (__bf16)a0hi.z; a0[7] = (__bf16)a0hi.w;
                a1[0] = (__bf16)a1lo.x; a1[1] = (__bf16)a1lo.y;
                a1[2] = (__bf16)a1lo.z; a1[3] = (__bf16)a1lo.w;
                a1[4] = (__bf16)a1hi.x; a1[5] = (__bf16)a1hi.y;
                a1[6] = (__bf16)a1hi.z; a1[7] = (__bf16)a1hi.w;
            }

            f32x4 c00 = {0.f, 0.f, 0.f, 0.f};
            f32x4 c01 = {0.f, 0.f, 0.f, 0.f};
            f32x4 c10 = {0.f, 0.f, 0.f, 0.f};
            f32x4 c11 = {0.f, 0.f, 0.f, 0.f};
            c00 = __builtin_amdgcn_mfma_f32_16x16x32_bf16(a0, b0, c00, 0, 0, 0);
            c01 = __builtin_amdgcn_mfma_f32_16x16x32_bf16(a0, b1, c01, 0, 0, 0);
            c10 = __builtin_amdgcn_mfma_f32_16x16x32_bf16(a1, b0, c10, 0, 0, 0);
            c11 = __builtin_amdgcn_mfma_f32_16x16x32_bf16(a1, b1, c11, 0, 0, 0);

            const unsigned rr0[4] = { rv0.x, rv0.y, rv0.z, rv0.w };
            const unsigned rr1[4] = { rv1.x, rv1.y, rv1.z, rv1.w };
#pragma unroll
            for (int r = 0; r < 4; ++r) {
                const int idx0  = s0 + quad * 4 + r;
                const int lrow0 = (idx0 < cnt) ? (int)((rr0[r] >> 19) & 255u) : CHROWS;
                lds_add_u64(&accw[lrow0 * ACCW + col], enc2(c00[r], c01[r]));
            }
#pragma unroll
            for (int r = 0; r < 4; ++r) {
                const int idx1  = s1 + quad * 4 + r;
                const int lrow1 = (idx1 < cnt) ? (int)((rr1[r] >> 19) & 255u) : CHROWS;
                lds_add_u64(&accw[lrow1 * ACCW + col], enc2(c10[r], c11[r]));
            }
        }
        for (; t < ntile; ++t) do_tile(t);
    }
    __syncthreads();

    // Decode + fused BN + ReLU: one u64 word (2 channels) per thread.
    if (tid < 512) {
        const int p  = tid & 15;            // ch-pair index
        const int c0 = 2 * p;
        const int r0 = tid >> 4;            // 0..31
        const float s0 = gamma[c0]     * rsqrtf(var[c0]     + 1e-5f);
        const float s1 = gamma[c0 + 1] * rsqrtf(var[c0 + 1] + 1e-5f);
        const float q0 = beta[c0]     - mean[c0]     * s0;
        const float q1 = beta[c0 + 1] - mean[c0 + 1] * s1;
#pragma unroll
        for (int it = 0; it < CHROWS / 32; ++it) {
            const int row  = it * 32 + r0;
            const int grow = c * CHROWS + row;
            if (grow < N) {
                long long t = (long long)accw[row * ACCW + p];
                const int d0 = (int)(unsigned)(t & 0xFFFFFFFFll);
                const int d1 = (int)((t - (long long)d0) >> 32);
                float2 o;
                o.x = fmaxf(fmaf((float)d0 * (1.f / 65536.f), s0, q0), 0.f);
                o.y = fmaxf(fmaf((float)d1 * (1.f / 65536.f), s1, q1), 0.f);
                *(float2*)(out + (size_t)grow * OUTC + c0) = o;
            }
        }
    }
}

// ------------------- pk-f16 atomic path (R3, 693us, fallback) ---------------
__global__ __launch_bounds__(256) void scatter_conv_mfma_pk(
    const float* __restrict__ feats,
    const float* __restrict__ wkern,
    const int*   __restrict__ in_idx,
    const int*   __restrict__ out_idx,
    __half2*     __restrict__ ws,
    int N)
{
    const int k    = blockIdx.y;
    const int lane = threadIdx.x & 63;
    const int col  = lane & 15;
    const int quad = lane >> 4;

    const int wave   = blockIdx.x * 4 + (threadIdx.x >> 6);
    const int nwaves = gridDim.x * 4;

    const float* wk = wkern + (size_t)k * (INC * OUTC);
    bf16x8 b0, b1;
#pragma unroll
    for (int j = 0; j < 8; ++j) {
        const int kk = quad * 8 + j;
        b0[j] = (__bf16)wk[kk * OUTC + 2 * col];
        b1[j] = (__bf16)wk[kk * OUTC + 2 * col + 1];
    }

    const int* iin_p  = in_idx  + (size_t)k * N;
    const int* iout_p = out_idx + (size_t)k * N;
    const int  ntiles = N >> 4;

    for (int t = wave; t < ntiles; t += nwaves) {
        const int base = t << 4;
        const int iin = iin_p[base + col];
        int orow[4];
#pragma unroll
        for (int r = 0; r < 4; ++r) orow[r] = iout_p[base + quad * 4 + r];

        const float4* ap = (const float4*)(feats + (size_t)iin * INC + quad * 8);
        const float4 a_lo = ap[0];
        const float4 a_hi = ap[1];
        bf16x8 a;
        a[0] = (__bf16)a_lo.x; a[1] = (__bf16)a_lo.y;
        a[2] = (__bf16)a_lo.z; a[3] = (__bf16)a_lo.w;
        a[4] = (__bf16)a_hi.x; a[5] = (__bf16)a_hi.y;
        a[6] = (__bf16)a_hi.z; a[7] = (__bf16)a_hi.w;

        f32x4 acc0 = {0.f, 0.f, 0.f, 0.f};
        f32x4 acc1 = {0.f, 0.f, 0.f, 0.f};
        acc0 = __builtin_amdgcn_mfma_f32_16x16x32_bf16(a, b0, acc0, 0, 0, 0);
        acc1 = __builtin_amdgcn_mfma_f32_16x16x32_bf16(a, b1, acc1, 0, 0, 0);

#pragma unroll
        for (int r = 0; r < 4; ++r) {
            __half2 v = __halves2half2(__float2half(acc0[r]), __float2half(acc1[r]));
            unsafeAtomicAdd(ws + (size_t)orow[r] * 16 + col, v);
        }
    }
}

__global__ __launch_bounds__(256) void bn_relu_f16(
    const __half2* __restrict__ ws,
    float* __restrict__ out,
    const float* __restrict__ gamma,
    const float* __restrict__ beta,
    const float* __restrict__ mean,
    const float* __restrict__ var,
    int total2)
{
    const int tid    = blockIdx.x * blockDim.x + threadIdx.x;
    const int stride = gridDim.x * blockDim.x;
    const int p      = tid & 15;
    const int c0     = 2 * p;

    float s0 = gamma[c0]     * rsqrtf(var[c0]     + 1e-5f);
    float s1 = gamma[c0 + 1] * rsqrtf(var[c0 + 1] + 1e-5f);
    float q0 = beta[c0]     - mean[c0]     * s0;
    float q1 = beta[c0 + 1] - mean[c0 + 1] * s1;

    float2* po = (float2*)out;
    for (int i = tid; i < total2; i += stride) {
        const __half2 h = ws[i];
        float2 v;
        v.x = fmaxf(fmaf(__low2float(h),  s0, q0), 0.0f);
        v.y = fmaxf(fmaf(__high2float(h), s1, q1), 0.0f);
        po[i] = v;
    }
}

// ------------------------- fp32 fallback (R2 path) -------------------------
__global__ __launch_bounds__(256) void scatter_conv_mfma_f32(
    const float* __restrict__ feats,
    const float* __restrict__ wkern,
    const int*   __restrict__ in_idx,
    const int*   __restrict__ out_idx,
    float*       __restrict__ out,
    int N)
{
    const int k    = blockIdx.y;
    const int lane = threadIdx.x & 63;
    const int col  = lane & 15;
    const int quad = lane >> 4;
    const int wave   = blockIdx.x * 4 + (threadIdx.x >> 6);
    const int nwaves = gridDim.x * 4;

    const float* wk = wkern + (size_t)k * (INC * OUTC);
    bf16x8 b0, b1;
#pragma unroll
    for (int j = 0; j < 8; ++j) {
        const int kk = quad * 8 + j;
        b0[j] = (__bf16)wk[kk * OUTC + col];
        b1[j] = (__bf16)wk[kk * OUTC + 16 + col];
    }

    const int* iin_p  = in_idx  + (size_t)k * N;
    const int* iout_p = out_idx + (size_t)k * N;
    const int  ntiles = N >> 4;

    for (int t = wave; t < ntiles; t += nwaves) {
        const int base = t << 4;
        const int iin = iin_p[base + col];
        int orow[4];
#pragma unroll
        for (int r = 0; r < 4; ++r) orow[r] = iout_p[base + quad * 4 + r];

        const float4* ap = (const float4*)(feats + (size_t)iin * INC + quad * 8);
        const float4 a_lo = ap[0];
        const float4 a_hi = ap[1];
        bf16x8 a;
        a[0] = (__bf16)a_lo.x; a[1] = (__bf16)a_lo.y;
        a[2] = (__bf16)a_lo.z; a[3] = (__bf16)a_lo.w;
        a[4] = (__bf16)a_hi.x; a[5] = (__bf16)a_hi.y;
        a[6] = (__bf16)a_hi.z; a[7] = (__bf16)a_hi.w;

        f32x4 acc0 = {0.f, 0.f, 0.f, 0.f};
        f32x4 acc1 = {0.f, 0.f, 0.f, 0.f};
        acc0 = __builtin_amdgcn_mfma_f32_16x16x32_bf16(a, b0, acc0, 0, 0, 0);
        acc1 = __builtin_amdgcn_mfma_f32_16x16x32_bf16(a, b1, acc1, 0, 0, 0);

#pragma unroll
        for (int r = 0; r < 4; ++r) {
            float* dst = out + (size_t)orow[r] * OUTC + col;
            unsafeAtomicAdd(dst,      acc0[r]);
            unsafeAtomicAdd(dst + 16, acc1[r]);
        }
    }
}

__global__ __launch_bounds__(256) void bn_relu_f32_inplace(
    float* __restrict__ out,
    const float* __restrict__ gamma,
    const float* __restrict__ beta,
    const float* __restrict__ mean,
    const float* __restrict__ var,
    int total4)
{
    const int tid    = blockIdx.x * blockDim.x + threadIdx.x;
    const int stride = gridDim.x * blockDim.x;
    const int c0     = (tid & 7) << 2;

    float s[4], b[4];
#pragma unroll
    for (int j = 0; j < 4; ++j) {
        const int c = c0 + j;
        s[j] = gamma[c] * rsqrtf(var[c] + 1e-5f);
        b[j] = beta[c] - mean[c] * s[j];
    }

    float4* p = (float4*)out;
    for (int i = tid; i < total4; i += stride) {
        float4 v = p[i];
        v.x = fmaxf(fmaf(v.x, s[0], b[0]), 0.0f);
        v.y = fmaxf(fmaf(v.y, s[1], b[1]), 0.0f);
        v.z = fmaxf(fmaf(v.z, s[2], b[2]), 0.0f);
        v.w = fmaxf(fmaf(v.w, s[3], b[3]), 0.0f);
        p[i] = v;
    }
}

extern "C" void kernel_launch(void* const* d_in, const int* in_sizes, int n_in,
                              void* d_out, int out_size, void* d_ws, size_t ws_size,
                              hipStream_t stream) {
    const float* feats   = (const float*)d_in[0];
    const float* wkern   = (const float*)d_in[1];
    const float* gamma   = (const float*)d_in[2];
    const float* beta    = (const float*)d_in[3];
    const float* mean    = (const float*)d_in[4];
    const float* var     = (const float*)d_in[5];
    const int*   in_idx  = (const int*)d_in[6];
    const int*   out_idx = (const int*)d_in[7];
    float*       out     = (float*)d_out;

    const int N = in_sizes[0] / INC;                  // 400000
    const int K = in_sizes[1] / (INC * OUTC);         // 27

    const int nchunk     = (N + CHROWS - 1) / CHROWS;       // 1563
    const int cps        = (nchunk + NSLICE - 1) / NSLICE;  // 196
    const int nchunkpad  = NSLICE * cps;                    // 1568
    const int slice_rows = cps * CHROWS;                    // 50176

    auto al = [](size_t x) { return (x + 255) & ~(size_t)255; };
    size_t off = 0;
    const size_t cntB_off  = off; off = al(off + (size_t)K * nchunkpad * 4);
    const size_t recsB_off = off; off = al(off + (size_t)K * nchunkpad * CAPB * 4);
    const size_t need_core = off;                           // ~65.2 MB
    const size_t fbf_off   = off;
    const size_t need_full = off + al((size_t)N * INC * 2); // ~90.8 MB
    const size_t need_pk   = (size_t)N * OUTC * sizeof(__half);

    const bool chunk_ok = (N <= (1 << 19)) && (N % 4 == 0) &&
                          (cps <= CPS_MAX) && (K == 27);

    if (chunk_ok && ws_size >= need_core) {
        char* base = (char*)d_ws;
        unsigned* cntB  = (unsigned*)(base + cntB_off);
        unsigned* recsB = (unsigned*)(base + recsB_off);

        const bool use_bf16 = ws_size >= need_full;
        if (use_bf16) {
            __bf16* fbf = (__bf16*)(base + fbf_off);
            fill_fused<true><<<dim3(NSLICE, K), 1024, 0, stream>>>(
                feats, fbf, in_idx, out_idx, recsB, cntB,
                N, cps, slice_rows, N * 4);
            conv_chunk<true><<<nchunk, 576, 0, stream>>>(
                feats, fbf, wkern, recsB, cntB, gamma, beta, mean, var,
                out, N, nchunkpad);
        } else {
            fill_fused<false><<<dim3(NSLICE, K), 1024, 0, stream>>>(
                feats, nullptr, in_idx, out_idx, recsB, cntB,
                N, cps, slice_rows, N * 4);
            conv_chunk<false><<<nchunk, 576, 0, stream>>>(
                feats, nullptr, wkern, recsB, cntB, gamma, beta, mean, var,
                out, N, nchunkpad);
        }
    } else if (ws_size >= need_pk) {
        __half2* acc = (__half2*)d_ws;
        hipMemsetAsync(acc, 0, need_pk, stream);
        dim3 grid(80, K);
        scatter_conv_mfma_pk<<<grid, 256, 0, stream>>>(
            feats, wkern, in_idx, out_idx, acc, N);
        bn_relu_f16<<<1024, 256, 0, stream>>>(acc, out, gamma, beta, mean, var, N * 16);
    } else {
        hipMemsetAsync(out, 0, (size_t)out_size * sizeof(float), stream);
        dim3 grid(80, K);
        scatter_conv_mfma_f32<<<grid, 256, 0, stream>>>(
            feats, wkern, in_idx, out_idx, out, N);
        bn_relu_f32_inplace<<<1024, 256, 0, stream>>>(
            out, gamma, beta, mean, var, out_size / 4);
    }
}